// Round 21
// baseline (347.966 us; speedup 1.0000x reference)
//
#include <hip/hip_runtime.h>
#include <hip/hip_bf16.h>
#include <math.h>

// InvGraphConv: SplineCNN block on MI355X.
// N=20000, E=320000, D=3, KS=5 -> K=125, S=8, Fin=Fout=32, hidden=64.
//
// R21: R20 base (325us) + register-cached edge metadata in fusedconv:
// each 8-lane group caches its first 2 edges' basis/idx/node/rs in VGPRs
// before the split loop (statically indexed), eliminating the per-split
// reload (4x for conv2, 2x for conv3); tail edges use the global path.

typedef short  s16x8 __attribute__((ext_vector_type(8)));
typedef float  f32x4 __attribute__((ext_vector_type(4)));
typedef _Float16 h16x2 __attribute__((ext_vector_type(2)));

__device__ __forceinline__ unsigned short f2b(float f) {
    __hip_bfloat16 h = __float2bfloat16(f);
    return __builtin_bit_cast(unsigned short, h);
}
__device__ __forceinline__ unsigned short f2h(float f) {
    _Float16 h = (_Float16)f;
    return __builtin_bit_cast(unsigned short, h);
}
__device__ __forceinline__ float h2f(unsigned short u) {
    _Float16 h = __builtin_bit_cast(_Float16, u);
    return (float)h;
}
__device__ __forceinline__ unsigned int fdup(float f) {
    unsigned int h = f2h(f);
    return h | (h << 16);
}
__device__ __forceinline__ h16x2 u2h2(unsigned int u) {
    return __builtin_bit_cast(h16x2, u);
}

__device__ __forceinline__ void spline8(const float u0, const float u1, const float u2,
                                        float* __restrict__ b, int* __restrict__ id) {
    const float u[3] = {u0, u1, u2};
    const int strides[3] = {25, 5, 1};
    float fr[3];
    int   i0[3];
#pragma unroll
    for (int d = 0; d < 3; ++d) {
        float p = u[d] * 4.0f;
        float f = floorf(p);
        f = fminf(fmaxf(f, 0.0f), 3.0f);
        i0[d] = (int)f;
        fr[d] = p - f;
    }
#pragma unroll
    for (int s = 0; s < 8; ++s) {
        float bb = 1.0f;
        int   ii = 0;
#pragma unroll
        for (int d = 0; d < 3; ++d) {
            int c = (s >> d) & 1;
            bb *= c ? fr[d] : (1.0f - fr[d]);
            ii += (i0[d] + c) * strides[d];
        }
        b[s] = bb;
        id[s] = ii;
    }
}

__global__ void hist_kernel(const int* __restrict__ row, const int* __restrict__ col,
                            int* __restrict__ histR, int* __restrict__ histC, int E) {
    int e = blockIdx.x * blockDim.x + threadIdx.x;
    if (e >= E) return;
    atomicAdd(&histR[row[e]], 1);
    atomicAdd(&histC[col[e]], 1);
}

// dual single-block exclusive scan
__global__ __launch_bounds__(1024) void scan2_kernel(
        const int* __restrict__ histC, const int* __restrict__ histR,
        int* __restrict__ cstart, int* __restrict__ cursorC,
        int* __restrict__ rowStart, int* __restrict__ cursorR, int N) {
    __shared__ int wsX[16], wsY[16];
    __shared__ int carX, carY;
    int t = threadIdx.x, lane = t & 63, w = t >> 6;
    if (t == 0) { carX = 0; carY = 0; }
    __syncthreads();
    for (int base = 0; base < N; base += 1024) {
        int i = base + t;
        int vx = (i < N) ? histC[i] : 0;
        int vy = (i < N) ? histR[i] : 0;
        int sx = vx, sy = vy;
#pragma unroll
        for (int off = 1; off < 64; off <<= 1) {
            int ux = __shfl_up(sx, off);
            int uy = __shfl_up(sy, off);
            if (lane >= off) { sx += ux; sy += uy; }
        }
        if (lane == 63) { wsX[w] = sx; wsY[w] = sy; }
        __syncthreads();
        if (w == 0 && lane < 16) {
            int ax = wsX[lane], ay = wsY[lane];
#pragma unroll
            for (int off = 1; off < 16; off <<= 1) {
                int ux = __shfl_up(ax, off);
                int uy = __shfl_up(ay, off);
                if (lane >= off) { ax += ux; ay += uy; }
            }
            wsX[lane] = ax; wsY[lane] = ay;
        }
        __syncthreads();
        int wx = (w > 0 ? wsX[w - 1] : 0) + carX;
        int wy = (w > 0 ? wsY[w - 1] : 0) + carY;
        if (i < N) {
            int ex = wx + sx - vx;
            int ey = wy + sy - vy;
            cstart[i] = ex; cursorC[i] = ex;
            rowStart[i] = ey; cursorR[i] = ey;
        }
        __syncthreads();
        if (t == 0) { carX += wsX[15]; carY += wsY[15]; }
        __syncthreads();
    }
}

// fused scatter + spline basis: col-sorted fp16-dup basisH/idx AND
// row-sorted f32 basisR/idxR (conv1); jpos kept for basis2.
__global__ void scatterbasis_kernel(
        const int* __restrict__ row, const int* __restrict__ col,
        const float* __restrict__ pseudo,
        int* __restrict__ cursorC, int* __restrict__ cursorR,
        int* __restrict__ jpos, int* __restrict__ colS, int* __restrict__ rs,
        unsigned int* __restrict__ basisH, unsigned char* __restrict__ idxb,
        float* __restrict__ basisR, unsigned char* __restrict__ idxR, int E) {
    int e = blockIdx.x * blockDim.x + threadIdx.x;
    if (e >= E) return;
    int c = col[e], r = row[e];
    int jc = atomicAdd(&cursorC[c], 1);
    int jr = atomicAdd(&cursorR[r], 1);
    jpos[e] = jc;
    colS[jc] = c;
    rs[jc] = jr;
    float b[8]; int id[8];
    spline8(pseudo[e * 3 + 0], pseudo[e * 3 + 1], pseudo[e * 3 + 2], b, id);
#pragma unroll
    for (int s = 0; s < 8; ++s) {
        basisH[(size_t)jc * 8 + s] = fdup(b[s]);
        idxb[(size_t)jc * 8 + s] = (unsigned char)id[s];
        basisR[(size_t)jr * 8 + s] = b[s];
        idxR[(size_t)jr * 8 + s] = (unsigned char)id[s];
    }
}

// fallback-only f32 basis
__global__ void basis1_kernel(const float* __restrict__ pseudo, const int* __restrict__ jpos,
                              float* __restrict__ basis, unsigned char* __restrict__ idxb, int E) {
    int e = blockIdx.x * blockDim.x + threadIdx.x;
    if (e >= E) return;
    float b[8]; int id[8];
    spline8(pseudo[e * 3 + 0], pseudo[e * 3 + 1], pseudo[e * 3 + 2], b, id);
    int j = jpos ? jpos[e] : e;
#pragma unroll
    for (int s = 0; s < 8; ++s) { basis[(size_t)j * 8 + s] = b[s]; idxb[(size_t)j * 8 + s] = (unsigned char)id[s]; }
}

// fast path: warped basis -> fp16-dup col-sorted
__global__ void basis2h_kernel(const float* __restrict__ pseudo, const float* __restrict__ t,
                               const int* __restrict__ row, const int* __restrict__ col,
                               const int* __restrict__ jpos,
                               unsigned int* __restrict__ basisH,
                               unsigned char* __restrict__ idxb, int E) {
    int e = blockIdx.x * blockDim.x + threadIdx.x;
    if (e >= E) return;
    int r = row[e], c = col[e];
    float u[3];
#pragma unroll
    for (int d = 0; d < 3; ++d) {
        float v = pseudo[e * 3 + d] + t[c * 3 + d] - t[r * 3 + d];
        u[d] = fminf(fmaxf(v, 0.0f), 1.0f);
    }
    float b[8]; int id[8];
    spline8(u[0], u[1], u[2], b, id);
    int j = jpos[e];
#pragma unroll
    for (int s = 0; s < 8; ++s) { basisH[(size_t)j * 8 + s] = fdup(b[s]); idxb[(size_t)j * 8 + s] = (unsigned char)id[s]; }
}

// fallback: warped basis f32
__global__ void basis2_kernel(const float* __restrict__ pseudo, const float* __restrict__ t,
                              const int* __restrict__ row, const int* __restrict__ col,
                              float* __restrict__ basis, unsigned char* __restrict__ idxb, int E) {
    int e = blockIdx.x * blockDim.x + threadIdx.x;
    if (e >= E) return;
    int r = row[e], c = col[e];
    float u[3];
#pragma unroll
    for (int d = 0; d < 3; ++d) {
        float v = pseudo[e * 3 + d] + t[c * 3 + d] - t[r * 3 + d];
        u[d] = fminf(fmaxf(v, 0.0f), 1.0f);
    }
    float b[8]; int id[8];
    spline8(u[0], u[1], u[2], b, id);
#pragma unroll
    for (int s = 0; s < 8; ++s) { basis[(size_t)e * 8 + s] = b[s]; idxb[(size_t)e * 8 + s] = (unsigned char)id[s]; }
}

__global__ void castbf_kernel(const float* __restrict__ in, unsigned short* __restrict__ out,
                              int n) {
    int t = blockIdx.x * blockDim.x + threadIdx.x;
    if (t < n) out[t] = f2b(in[t]);
}

// Pack W [Kc][Fin][Fout] fp32 -> MFMA B-fragments bf16, channel-split order.
__global__ void pack_w_kernel(const float* __restrict__ W, unsigned short* __restrict__ BF,
                              int Kc, int Fin, int Fout, int ksteps, int CH) {
    int t = blockIdx.x * blockDim.x + threadIdx.x;
    int total = Kc * Fout * Fin;
    if (t >= total) return;
    int c = t / Fin;
    int i = t % Fin;
    int kk = c / Fout, o = c % Fout;
    int split = o / CH;
    int cp = split * (Kc * CH) + kk * CH + (o % CH);
    int ct = cp >> 4, lr = cp & 15;
    int step = i >> 5, rem = i & 31, lg = rem >> 3, jj = rem & 7;
    size_t dst = ((((size_t)ct * ksteps + step) * 4 + lg) * 16 + lr) * 8 + jj;
    BF[dst] = f2b(W[((size_t)kk * Fin + i) * Fout + o]);
}

// conv1 phase B: W1 in LDS; wave per row-node; streams row-sorted basisR/idxR.
__global__ __launch_bounds__(512) void phaseB1s_kernel(
        const float* __restrict__ W1, const float* __restrict__ basisR,
        const unsigned char* __restrict__ idxR, const int* __restrict__ rowStart,
        const int* __restrict__ histR, const float* __restrict__ b1,
        unsigned short* __restrict__ h1b, int N) {
    __shared__ float w[125 * 64];
    for (int i = threadIdx.x; i < 125 * 64; i += 512) w[i] = W1[i];
    __syncthreads();
    int n = blockIdx.x * 8 + (threadIdx.x >> 6);
    if (n >= N) return;
    int l = threadIdx.x & 63;
    int s0 = rowStart[n], cnt = histR[n];
    float a = 0.0f;
    for (int i = 0; i < cnt; ++i) {
        const float4* bp = (const float4*)(basisR + (size_t)(s0 + i) * 8);
        float4 b0 = bp[0], b1v = bp[1];
        const uchar4* ip = (const uchar4*)(idxR + (size_t)(s0 + i) * 8);
        uchar4 i0 = ip[0], i1 = ip[1];
        a += b0.x * w[i0.x * 64 + l] + b0.y * w[i0.y * 64 + l]
           + b0.z * w[i0.z * 64 + l] + b0.w * w[i0.w * 64 + l]
           + b1v.x * w[i1.x * 64 + l] + b1v.y * w[i1.y * 64 + l]
           + b1v.z * w[i1.z * 64 + l] + b1v.w * w[i1.w * 64 + l];
    }
    float v = a / fmaxf((float)cnt, 1.0f) + b1[l];
    v = (v > 0.0f) ? v : (expf(v) - 1.0f);
    h1b[(size_t)n * 64 + l] = f2b(v);
}

// fused conv: 1024 threads (16 waves), block owns 16 col-nodes.
// Edge metadata for each group's first 2 edges cached in registers across
// the split loop; per split: MFMA fills ztile, edge pass -> msgP[s].
template<int KSTEPS, int SPLITS>
__global__ __launch_bounds__(1024) void fusedconv_kernel(
        const unsigned short* __restrict__ A,
        const unsigned short* __restrict__ BF,
        const unsigned int* __restrict__ basisH, const unsigned char* __restrict__ idxb,
        const int* __restrict__ cstart, const int* __restrict__ colS,
        const int* __restrict__ rs,
        unsigned short* __restrict__ msgP, int N, int E) {
    const int ZLD = 2008;
    const int MAXE = 2;
    __shared__ unsigned short ztile[16 * 2008];   // 64,256 B
    int n0 = blockIdx.x * 16;
    if (n0 >= N) return;
    int w = threadIdx.x >> 6, l = threadIdx.x & 63;
    int lr = l & 15, lg = l >> 4;
    const int KD = KSTEPS * 32;
    int arow = n0 + lr; if (arow > N - 1) arow = N - 1;
    s16x8 a[KSTEPS];
#pragma unroll
    for (int st = 0; st < KSTEPS; ++st)
        a[st] = *(const s16x8*)(A + (size_t)arow * KD + st * 32 + lg * 8);
    int estart = cstart[n0];
    int eend = (n0 + 16 < N) ? cstart[n0 + 16] : E;
    int g = threadIdx.x >> 3, chp = threadIdx.x & 7;   // 128 groups x 8 ch-pairs
    // ---- register-cache the group's first MAXE edges ----
    uint4 cbA[MAXE], cbB[MAXE];
    uchar4 ci0[MAXE], ci1[MAXE];
    int cnode[MAXE], crs[MAXE];
    int ne = 0;
    {
        int j = estart + g;
#pragma unroll
        for (int k = 0; k < MAXE; ++k, j += 128) {
            if (j < eend) {
                const uint4* bhp = (const uint4*)(basisH + (size_t)j * 8);
                cbA[k] = bhp[0]; cbB[k] = bhp[1];
                const uchar4* ip = (const uchar4*)(idxb + (size_t)j * 8);
                ci0[k] = ip[0]; ci1[k] = ip[1];
                cnode[k] = colS[j] - n0;
                crs[k] = rs[j];
                ne = k + 1;
            }
        }
    }
    for (int s = 0; s < SPLITS; ++s) {
        for (int ct = w; ct < 125; ct += 16) {
            f32x4 acc = (f32x4){0.f, 0.f, 0.f, 0.f};
#pragma unroll
            for (int st = 0; st < KSTEPS; ++st) {
                const unsigned short* bp =
                    BF + ((((size_t)(s * 125 + ct) * KSTEPS + st) * 4 + lg) * 16 + lr) * 8;
                s16x8 b = *(const s16x8*)bp;
                acc = __builtin_amdgcn_mfma_f32_16x16x32_bf16(a[st], b, acc, 0, 0, 0);
            }
#pragma unroll
            for (int r = 0; r < 4; ++r)
                ztile[(lg * 4 + r) * ZLD + ct * 16 + lr] = f2h(acc[r]);
        }
        __syncthreads();
        unsigned int* mp = (unsigned int*)(msgP + (size_t)s * E * 16);
        // cached edges (statically indexed)
#pragma unroll
        for (int k = 0; k < MAXE; ++k) {
            if (k < ne) {
                const unsigned int* zr = (const unsigned int*)(ztile + cnode[k] * ZLD);
                unsigned int v0 = zr[ci0[k].x * 8 + chp];
                unsigned int v1 = zr[ci0[k].y * 8 + chp];
                unsigned int v2 = zr[ci0[k].z * 8 + chp];
                unsigned int v3 = zr[ci0[k].w * 8 + chp];
                unsigned int v4 = zr[ci1[k].x * 8 + chp];
                unsigned int v5 = zr[ci1[k].y * 8 + chp];
                unsigned int v6 = zr[ci1[k].z * 8 + chp];
                unsigned int v7 = zr[ci1[k].w * 8 + chp];
                h16x2 ta = u2h2(cbA[k].x) * u2h2(v0);
                ta = u2h2(cbA[k].y) * u2h2(v1) + ta;
                ta = u2h2(cbA[k].z) * u2h2(v2) + ta;
                ta = u2h2(cbA[k].w) * u2h2(v3) + ta;
                h16x2 tb = u2h2(cbB[k].x) * u2h2(v4);
                tb = u2h2(cbB[k].y) * u2h2(v5) + tb;
                tb = u2h2(cbB[k].z) * u2h2(v6) + tb;
                tb = u2h2(cbB[k].w) * u2h2(v7) + tb;
                h16x2 m = ta + tb;
                mp[(size_t)crs[k] * 8 + chp] = __builtin_bit_cast(unsigned int, m);
            }
        }
        // tail edges (global path)
        for (int j = estart + g + MAXE * 128; j < eend; j += 128) {
            int node = colS[j] - n0;
            const uint4* bhp = (const uint4*)(basisH + (size_t)j * 8);
            uint4 bA = bhp[0], bB = bhp[1];
            const uchar4* ip = (const uchar4*)(idxb + (size_t)j * 8);
            uchar4 i0 = ip[0], i1 = ip[1];
            const unsigned int* zr = (const unsigned int*)(ztile + node * ZLD);
            unsigned int v0 = zr[i0.x * 8 + chp];
            unsigned int v1 = zr[i0.y * 8 + chp];
            unsigned int v2 = zr[i0.z * 8 + chp];
            unsigned int v3 = zr[i0.w * 8 + chp];
            unsigned int v4 = zr[i1.x * 8 + chp];
            unsigned int v5 = zr[i1.y * 8 + chp];
            unsigned int v6 = zr[i1.z * 8 + chp];
            unsigned int v7 = zr[i1.w * 8 + chp];
            h16x2 ta = u2h2(bA.x) * u2h2(v0);
            ta = u2h2(bA.y) * u2h2(v1) + ta;
            ta = u2h2(bA.z) * u2h2(v2) + ta;
            ta = u2h2(bA.w) * u2h2(v3) + ta;
            h16x2 tb = u2h2(bB.x) * u2h2(v4);
            tb = u2h2(bB.y) * u2h2(v5) + tb;
            tb = u2h2(bB.z) * u2h2(v6) + tb;
            tb = u2h2(bB.w) * u2h2(v7) + tb;
            h16x2 m = ta + tb;
            mp[(size_t)rs[j] * 8 + chp] = __builtin_bit_cast(unsigned int, m);
        }
        __syncthreads();
    }
}

// phase B conv2 + fused stn3/stn4 -> tt. Reads 4 split-major msg planes.
__global__ __launch_bounds__(256) void phaseBs2stn_kernel(
        const unsigned short* __restrict__ msgP, const int* __restrict__ rowStart,
        const int* __restrict__ histR, const float* __restrict__ b2,
        const float* __restrict__ w3, const float* __restrict__ b3,
        const float* __restrict__ w4, const float* __restrict__ b4,
        float* __restrict__ tt, int N, int E) {
    __shared__ float sh[4][64];
    __shared__ float sh3[4][64];
    int wid = threadIdx.x >> 6, l = threadIdx.x & 63;
    int n = blockIdx.x * 4 + wid;
    if (n >= N) return;
    int s0 = rowStart[n], cnt = histR[n];
    const unsigned short* mp = msgP + (size_t)(l >> 4) * E * 16 + (l & 15);
    float a = 0.0f;
    for (int i = 0; i < cnt; ++i)
        a += h2f(mp[(size_t)(s0 + i) * 16]);
    float v = a / fmaxf((float)cnt, 1.0f) + b2[l];
    v = (v > 0.0f) ? v : (expf(v) - 1.0f);
    sh[wid][l] = v;
    __builtin_amdgcn_wave_barrier();
    float v3 = b3[l];
#pragma unroll
    for (int i = 0; i < 64; ++i) v3 += sh[wid][i] * w3[i * 64 + l];
    v3 = (v3 > 0.0f) ? v3 : (expf(v3) - 1.0f);
    sh3[wid][l] = v3;
    __builtin_amdgcn_wave_barrier();
    if (l < 3) {
        float tv = b4[l];
#pragma unroll
        for (int i = 0; i < 64; ++i) tv += sh3[wid][i] * w4[i * 3 + l];
        tt[(size_t)n * 3 + l] = tv;
    }
}

// phase B conv3: half-wave per node; reads 2 split-major planes; mean+bias.
__global__ __launch_bounds__(256) void phaseBs3p_kernel(
        const unsigned short* __restrict__ msgP, const int* __restrict__ rowStart,
        const int* __restrict__ histR, const float* __restrict__ bias,
        float* __restrict__ out, int N, int E) {
    int n = blockIdx.x * 8 + (threadIdx.x >> 5);
    if (n >= N) return;
    int l = threadIdx.x & 31;
    int s0 = rowStart[n], cnt = histR[n];
    const unsigned short* mp = msgP + (size_t)(l >> 4) * E * 16 + (l & 15);
    float a = 0.0f;
    for (int i = 0; i < cnt; ++i)
        a += h2f(mp[(size_t)(s0 + i) * 16]);
    out[(size_t)n * 32 + l] = a / fmaxf((float)cnt, 1.0f) + bias[l];
}

// stn3 + stn4 per node (fallback path only)
__global__ __launch_bounds__(64) void stn34_kernel(
        const float* __restrict__ h2, const float* __restrict__ w3,
        const float* __restrict__ b3, const float* __restrict__ w4,
        const float* __restrict__ b4, float* __restrict__ t, int N) {
    int n = blockIdx.x;
    int o = threadIdx.x;
    __shared__ float sh[64];
    __shared__ float sh3[64];
    sh[o] = h2[n * 64 + o];
    __syncthreads();
    float v = b3[o];
#pragma unroll
    for (int i = 0; i < 64; ++i) v += sh[i] * w3[i * 64 + o];
    v = (v > 0.0f) ? v : (expf(v) - 1.0f);
    sh3[o] = v;
    __syncthreads();
    if (o < 3) {
        float tv = b4[o];
#pragma unroll
        for (int i = 0; i < 64; ++i) tv += sh3[i] * w4[i * 3 + o];
        t[n * 3 + o] = tv;
    }
}

// ---- minimal fallback (only if ws is tiny; direct, correct) ----
__global__ __launch_bounds__(256) void conv1_at_kernel(
        const float* __restrict__ basis, const unsigned char* __restrict__ idxb,
        const int* __restrict__ row, const float* __restrict__ W1,
        float* __restrict__ acc, int E) {
    int j = blockIdx.x * 4 + (threadIdx.x >> 6);
    if (j >= E) return;
    int l = threadIdx.x & 63;
    float m = 0.0f;
#pragma unroll
    for (int s = 0; s < 8; ++s) m += basis[(size_t)j * 8 + s] * W1[idxb[(size_t)j * 8 + s] * 64 + l];
    atomicAdd(&acc[(size_t)row[j] * 64 + l], m);
}

__global__ __launch_bounds__(256) void conv2f_kernel(
        const float* __restrict__ h1, const float* __restrict__ basis,
        const unsigned char* __restrict__ idxb, const int* __restrict__ row,
        const int* __restrict__ col, const float* __restrict__ W2,
        float* __restrict__ acc, int E) {
    int wid = threadIdx.x >> 6;
    int lane = threadIdx.x & 63;
    int e = blockIdx.x * 4 + wid;
    __shared__ float sh[4][64];
    bool active = (e < E);
    int c = active ? col[e] : 0;
    if (active) sh[wid][lane] = h1[(size_t)c * 64 + lane];
    __syncthreads();
    if (!active) return;
    float m = 0.0f;
#pragma unroll
    for (int s = 0; s < 8; ++s) {
        const float* Wk = W2 + (size_t)idxb[(size_t)e * 8 + s] * 4096;
        float ms = 0.0f;
#pragma unroll
        for (int i = 0; i < 64; ++i) ms += sh[wid][i] * Wk[i * 64 + lane];
        m += basis[(size_t)e * 8 + s] * ms;
    }
    atomicAdd(&acc[(size_t)row[e] * 64 + lane], m);
}

__global__ __launch_bounds__(256) void conv3f_kernel(
        const float* __restrict__ x, const float* __restrict__ basis,
        const unsigned char* __restrict__ idxb, const int* __restrict__ row,
        const int* __restrict__ col, const float* __restrict__ Wc,
        float* __restrict__ acc, int E) {
    int wid = threadIdx.x >> 6;
    int lane = threadIdx.x & 63;
    int e = blockIdx.x * 4 + wid;
    __shared__ float sx[4][32];
    bool active = (e < E);
    int c = active ? col[e] : 0;
    if (active && lane < 32) sx[wid][lane] = x[(size_t)c * 32 + lane];
    __syncthreads();
    int half = lane >> 5;
    int o = lane & 31;
    float m = 0.0f;
    if (active) {
#pragma unroll
        for (int s2 = 0; s2 < 4; ++s2) {
            int s = half * 4 + s2;
            const float* Wk = Wc + (size_t)idxb[(size_t)e * 8 + s] * 1024;
            float ms = 0.0f;
#pragma unroll
            for (int i = 0; i < 32; ++i) ms += sx[wid][i] * Wk[i * 32 + o];
            m += basis[(size_t)e * 8 + s] * ms;
        }
    }
    m += __shfl_xor(m, 32);
    if (active && lane < 32) atomicAdd(&acc[(size_t)row[e] * 32 + o], m);
}

__global__ void finalize_kernel(const float* __restrict__ acc, const int* __restrict__ histR,
                                const float* __restrict__ bias, float* __restrict__ outF,
                                unsigned short* __restrict__ outB,
                                int N, int F, int do_elu) {
    int t = blockIdx.x * blockDim.x + threadIdx.x;
    if (t >= N * F) return;
    int n = t / F, o = t % F;
    float v = acc[t] / fmaxf((float)histR[n], 1.0f) + bias[o];
    if (do_elu) v = (v > 0.0f) ? v : (expf(v) - 1.0f);
    if (outF) outF[t] = v;
    if (outB) outB[t] = f2b(v);
}

extern "C" void kernel_launch(void* const* d_in, const int* in_sizes, int n_in,
                              void* d_out, int out_size, void* d_ws, size_t ws_size,
                              hipStream_t stream) {
    const float* x      = (const float*)d_in[0];
    const int*   ei     = (const int*)d_in[1];
    const float* pseudo = (const float*)d_in[2];
    const float* w1     = (const float*)d_in[3];
    const float* b1     = (const float*)d_in[4];
    const float* w2     = (const float*)d_in[5];
    const float* b2     = (const float*)d_in[6];
    const float* w3     = (const float*)d_in[7];
    const float* b3     = (const float*)d_in[8];
    const float* w4     = (const float*)d_in[9];
    const float* b4     = (const float*)d_in[10];
    const float* wc     = (const float*)d_in[11];
    const float* cb     = (const float*)d_in[12];
    float* out = (float*)d_out;

    const int N = in_sizes[0] / 32;
    const int E = in_sizes[1] / 2;
    const int* row = ei;
    const int* col = ei + E;
    const int KC = 125;

    char* p = (char*)d_ws;
    // zeroed: histograms
    int* histR = (int*)p; p += (size_t)N * sizeof(int);
    int* histC = (int*)p; p += (size_t)N * sizeof(int);
    size_t zero_bytes = (size_t)(p - (char*)d_ws);
    // non-zeroed
    int* cstart   = (int*)p; p += (size_t)N * sizeof(int);
    int* cursorC  = (int*)p; p += (size_t)N * sizeof(int);
    int* rowStart = (int*)p; p += (size_t)N * sizeof(int);
    int* cursorR  = (int*)p; p += (size_t)N * sizeof(int);
    int* jpos = (int*)p; p += (size_t)E * sizeof(int);
    int* colS = (int*)p; p += (size_t)E * sizeof(int);
    int* rs   = (int*)p; p += (size_t)E * sizeof(int);
    float* tt = (float*)p; p += (size_t)N * 3 * sizeof(float);
    // col-sorted basis: fp16-dup u32 in fast path; f32 in fallback (same bytes)
    unsigned int* basisH = (unsigned int*)p;
    float* basisF = (float*)p; p += (size_t)E * 8 * sizeof(float);
    unsigned char* idxb = (unsigned char*)p; p += (size_t)E * 8;
    unsigned short* h1b = (unsigned short*)p; p += (size_t)N * 64 * sizeof(short);
    unsigned short* xb  = (unsigned short*)p; p += (size_t)N * 32 * sizeof(short);
    unsigned short* BF2 = (unsigned short*)p; p += (size_t)KC * 64 * 64 * sizeof(short);
    unsigned short* BF3 = (unsigned short*)p; p += (size_t)KC * 32 * 32 * sizeof(short);
    unsigned short* msg = (unsigned short*)p; p += (size_t)E * 64 * sizeof(short);
    float* basisR = (float*)p; p += (size_t)E * 8 * sizeof(float);
    unsigned char* idxR = (unsigned char*)p; p += (size_t)E * 8;
    size_t fixed = (size_t)(p - (char*)d_ws);
    bool fast = ws_size >= fixed;

    hipMemsetAsync(d_ws, 0, zero_bytes, stream);
    hist_kernel<<<(E + 255) / 256, 256, 0, stream>>>(row, col, histR, histC, E);

    if (fast) {
        pack_w_kernel<<<(KC * 64 * 64 + 255) / 256, 256, 0, stream>>>(w2, BF2, KC, 64, 64, 2, 16);
        pack_w_kernel<<<(KC * 32 * 32 + 255) / 256, 256, 0, stream>>>(wc, BF3, KC, 32, 32, 1, 16);
        castbf_kernel<<<(N * 32 + 255) / 256, 256, 0, stream>>>(x, xb, N * 32);

        scan2_kernel<<<1, 1024, 0, stream>>>(histC, histR, cstart, cursorC, rowStart, cursorR, N);
        scatterbasis_kernel<<<(E + 255) / 256, 256, 0, stream>>>(
            row, col, pseudo, cursorC, cursorR, jpos, colS, rs, basisH, idxb, basisR, idxR, E);

        // conv1: streaming row-sorted basis vs LDS W1 (512 thr, 32 waves/CU)
        phaseB1s_kernel<<<(N + 7) / 8, 512, 0, stream>>>(w1, basisR, idxR, rowStart,
                                                         histR, b1, h1b, N);
        const int NB = (N + 15) / 16;
        // conv2: fused MFMA-in-LDS, 4 splits, 1024 threads, reg-cached edges
        fusedconv_kernel<2, 4><<<NB, 1024, 0, stream>>>(
            h1b, BF2, basisH, idxb, cstart, colS, rs, msg, N, E);
        phaseBs2stn_kernel<<<(N + 3) / 4, 256, 0, stream>>>(msg, rowStart, histR, b2,
                                                            w3, b3, w4, b4, tt, N, E);
        basis2h_kernel<<<(E + 255) / 256, 256, 0, stream>>>(pseudo, tt, row, col, jpos,
                                                            basisH, idxb, E);
        // conv3: fused MFMA-in-LDS, 2 splits, 1024 threads, reg-cached edges
        fusedconv_kernel<1, 2><<<NB, 1024, 0, stream>>>(
            xb, BF3, basisH, idxb, cstart, colS, rs, msg, N, E);
        phaseBs3p_kernel<<<(N + 7) / 8, 256, 0, stream>>>(msg, rowStart, histR, cb, out, N, E);
    } else {
        // tiny-ws fallback: direct convs with atomics (correct, slow)
        float* acc1 = (float*)msg;
        float* acc2 = acc1 + (size_t)N * 64;
        float* acc3 = acc2 + (size_t)N * 64;
        float* h1f  = acc3 + (size_t)N * 32;
        float* h2f_ = h1f  + (size_t)N * 64;
        size_t acc_bytes = (size_t)N * (64 + 64 + 32) * sizeof(float);
        hipMemsetAsync((void*)acc1, 0, acc_bytes, stream);

        basis1_kernel<<<(E + 255) / 256, 256, 0, stream>>>(pseudo, nullptr, basisF, idxb, E);
        conv1_at_kernel<<<(E + 3) / 4, 256, 0, stream>>>(basisF, idxb, row, w1, acc1, E);
        finalize_kernel<<<(N * 64 + 255) / 256, 256, 0, stream>>>(acc1, histR, b1, h1f, nullptr, N, 64, 1);
        conv2f_kernel<<<(E + 3) / 4, 256, 0, stream>>>(h1f, basisF, idxb, row, col, w2, acc2, E);
        finalize_kernel<<<(N * 64 + 255) / 256, 256, 0, stream>>>(acc2, histR, b2, h2f_, nullptr, N, 64, 1);
        stn34_kernel<<<N, 64, 0, stream>>>(h2f_, w3, b3, w4, b4, tt, N);
        basis2_kernel<<<(E + 255) / 256, 256, 0, stream>>>(pseudo, tt, row, col, basisF, idxb, E);
        conv3f_kernel<<<(E + 3) / 4, 256, 0, stream>>>(x, basisF, idxb, row, col, wc, acc3, E);
        finalize_kernel<<<(N * 32 + 255) / 256, 256, 0, stream>>>(acc3, histR, cb, out, nullptr, N, 32, 0);
    }
}

// Round 22
// 324.936 us; speedup vs baseline: 1.0709x; 1.0709x over previous
//
#include <hip/hip_runtime.h>
#include <hip/hip_bf16.h>
#include <math.h>

// InvGraphConv: SplineCNN block on MI355X.
// N=20000, E=320000, D=3, KS=5 -> K=125, S=8, Fin=Fout=32, hidden=64.
//
// R22: exact revert to R20 (best measured: 325us). NODES=16 fusedconv at
// 1024 threads (2 blocks/CU, 32 waves/CU), packed-fp16 edge math,
// split-major msg planes, dual-sort atomic-free message passing.

typedef short  s16x8 __attribute__((ext_vector_type(8)));
typedef float  f32x4 __attribute__((ext_vector_type(4)));
typedef _Float16 h16x2 __attribute__((ext_vector_type(2)));

__device__ __forceinline__ unsigned short f2b(float f) {
    __hip_bfloat16 h = __float2bfloat16(f);
    return __builtin_bit_cast(unsigned short, h);
}
__device__ __forceinline__ unsigned short f2h(float f) {
    _Float16 h = (_Float16)f;
    return __builtin_bit_cast(unsigned short, h);
}
__device__ __forceinline__ float h2f(unsigned short u) {
    _Float16 h = __builtin_bit_cast(_Float16, u);
    return (float)h;
}
__device__ __forceinline__ unsigned int fdup(float f) {
    unsigned int h = f2h(f);
    return h | (h << 16);
}
__device__ __forceinline__ h16x2 u2h2(unsigned int u) {
    return __builtin_bit_cast(h16x2, u);
}

__device__ __forceinline__ void spline8(const float u0, const float u1, const float u2,
                                        float* __restrict__ b, int* __restrict__ id) {
    const float u[3] = {u0, u1, u2};
    const int strides[3] = {25, 5, 1};
    float fr[3];
    int   i0[3];
#pragma unroll
    for (int d = 0; d < 3; ++d) {
        float p = u[d] * 4.0f;
        float f = floorf(p);
        f = fminf(fmaxf(f, 0.0f), 3.0f);
        i0[d] = (int)f;
        fr[d] = p - f;
    }
#pragma unroll
    for (int s = 0; s < 8; ++s) {
        float bb = 1.0f;
        int   ii = 0;
#pragma unroll
        for (int d = 0; d < 3; ++d) {
            int c = (s >> d) & 1;
            bb *= c ? fr[d] : (1.0f - fr[d]);
            ii += (i0[d] + c) * strides[d];
        }
        b[s] = bb;
        id[s] = ii;
    }
}

__global__ void hist_kernel(const int* __restrict__ row, const int* __restrict__ col,
                            int* __restrict__ histR, int* __restrict__ histC, int E) {
    int e = blockIdx.x * blockDim.x + threadIdx.x;
    if (e >= E) return;
    atomicAdd(&histR[row[e]], 1);
    atomicAdd(&histC[col[e]], 1);
}

// dual single-block exclusive scan
__global__ __launch_bounds__(1024) void scan2_kernel(
        const int* __restrict__ histC, const int* __restrict__ histR,
        int* __restrict__ cstart, int* __restrict__ cursorC,
        int* __restrict__ rowStart, int* __restrict__ cursorR, int N) {
    __shared__ int wsX[16], wsY[16];
    __shared__ int carX, carY;
    int t = threadIdx.x, lane = t & 63, w = t >> 6;
    if (t == 0) { carX = 0; carY = 0; }
    __syncthreads();
    for (int base = 0; base < N; base += 1024) {
        int i = base + t;
        int vx = (i < N) ? histC[i] : 0;
        int vy = (i < N) ? histR[i] : 0;
        int sx = vx, sy = vy;
#pragma unroll
        for (int off = 1; off < 64; off <<= 1) {
            int ux = __shfl_up(sx, off);
            int uy = __shfl_up(sy, off);
            if (lane >= off) { sx += ux; sy += uy; }
        }
        if (lane == 63) { wsX[w] = sx; wsY[w] = sy; }
        __syncthreads();
        if (w == 0 && lane < 16) {
            int ax = wsX[lane], ay = wsY[lane];
#pragma unroll
            for (int off = 1; off < 16; off <<= 1) {
                int ux = __shfl_up(ax, off);
                int uy = __shfl_up(ay, off);
                if (lane >= off) { ax += ux; ay += uy; }
            }
            wsX[lane] = ax; wsY[lane] = ay;
        }
        __syncthreads();
        int wx = (w > 0 ? wsX[w - 1] : 0) + carX;
        int wy = (w > 0 ? wsY[w - 1] : 0) + carY;
        if (i < N) {
            int ex = wx + sx - vx;
            int ey = wy + sy - vy;
            cstart[i] = ex; cursorC[i] = ex;
            rowStart[i] = ey; cursorR[i] = ey;
        }
        __syncthreads();
        if (t == 0) { carX += wsX[15]; carY += wsY[15]; }
        __syncthreads();
    }
}

// fused scatter + spline basis: col-sorted fp16-dup basisH/idx AND
// row-sorted f32 basisR/idxR (conv1); jpos kept for basis2.
__global__ void scatterbasis_kernel(
        const int* __restrict__ row, const int* __restrict__ col,
        const float* __restrict__ pseudo,
        int* __restrict__ cursorC, int* __restrict__ cursorR,
        int* __restrict__ jpos, int* __restrict__ colS, int* __restrict__ rs,
        unsigned int* __restrict__ basisH, unsigned char* __restrict__ idxb,
        float* __restrict__ basisR, unsigned char* __restrict__ idxR, int E) {
    int e = blockIdx.x * blockDim.x + threadIdx.x;
    if (e >= E) return;
    int c = col[e], r = row[e];
    int jc = atomicAdd(&cursorC[c], 1);
    int jr = atomicAdd(&cursorR[r], 1);
    jpos[e] = jc;
    colS[jc] = c;
    rs[jc] = jr;
    float b[8]; int id[8];
    spline8(pseudo[e * 3 + 0], pseudo[e * 3 + 1], pseudo[e * 3 + 2], b, id);
#pragma unroll
    for (int s = 0; s < 8; ++s) {
        basisH[(size_t)jc * 8 + s] = fdup(b[s]);
        idxb[(size_t)jc * 8 + s] = (unsigned char)id[s];
        basisR[(size_t)jr * 8 + s] = b[s];
        idxR[(size_t)jr * 8 + s] = (unsigned char)id[s];
    }
}

// fallback-only f32 basis
__global__ void basis1_kernel(const float* __restrict__ pseudo, const int* __restrict__ jpos,
                              float* __restrict__ basis, unsigned char* __restrict__ idxb, int E) {
    int e = blockIdx.x * blockDim.x + threadIdx.x;
    if (e >= E) return;
    float b[8]; int id[8];
    spline8(pseudo[e * 3 + 0], pseudo[e * 3 + 1], pseudo[e * 3 + 2], b, id);
    int j = jpos ? jpos[e] : e;
#pragma unroll
    for (int s = 0; s < 8; ++s) { basis[(size_t)j * 8 + s] = b[s]; idxb[(size_t)j * 8 + s] = (unsigned char)id[s]; }
}

// fast path: warped basis -> fp16-dup col-sorted
__global__ void basis2h_kernel(const float* __restrict__ pseudo, const float* __restrict__ t,
                               const int* __restrict__ row, const int* __restrict__ col,
                               const int* __restrict__ jpos,
                               unsigned int* __restrict__ basisH,
                               unsigned char* __restrict__ idxb, int E) {
    int e = blockIdx.x * blockDim.x + threadIdx.x;
    if (e >= E) return;
    int r = row[e], c = col[e];
    float u[3];
#pragma unroll
    for (int d = 0; d < 3; ++d) {
        float v = pseudo[e * 3 + d] + t[c * 3 + d] - t[r * 3 + d];
        u[d] = fminf(fmaxf(v, 0.0f), 1.0f);
    }
    float b[8]; int id[8];
    spline8(u[0], u[1], u[2], b, id);
    int j = jpos[e];
#pragma unroll
    for (int s = 0; s < 8; ++s) { basisH[(size_t)j * 8 + s] = fdup(b[s]); idxb[(size_t)j * 8 + s] = (unsigned char)id[s]; }
}

// fallback: warped basis f32
__global__ void basis2_kernel(const float* __restrict__ pseudo, const float* __restrict__ t,
                              const int* __restrict__ row, const int* __restrict__ col,
                              float* __restrict__ basis, unsigned char* __restrict__ idxb, int E) {
    int e = blockIdx.x * blockDim.x + threadIdx.x;
    if (e >= E) return;
    int r = row[e], c = col[e];
    float u[3];
#pragma unroll
    for (int d = 0; d < 3; ++d) {
        float v = pseudo[e * 3 + d] + t[c * 3 + d] - t[r * 3 + d];
        u[d] = fminf(fmaxf(v, 0.0f), 1.0f);
    }
    float b[8]; int id[8];
    spline8(u[0], u[1], u[2], b, id);
#pragma unroll
    for (int s = 0; s < 8; ++s) { basis[(size_t)e * 8 + s] = b[s]; idxb[(size_t)e * 8 + s] = (unsigned char)id[s]; }
}

__global__ void castbf_kernel(const float* __restrict__ in, unsigned short* __restrict__ out,
                              int n) {
    int t = blockIdx.x * blockDim.x + threadIdx.x;
    if (t < n) out[t] = f2b(in[t]);
}

// Pack W [Kc][Fin][Fout] fp32 -> MFMA B-fragments bf16, channel-split order.
__global__ void pack_w_kernel(const float* __restrict__ W, unsigned short* __restrict__ BF,
                              int Kc, int Fin, int Fout, int ksteps, int CH) {
    int t = blockIdx.x * blockDim.x + threadIdx.x;
    int total = Kc * Fout * Fin;
    if (t >= total) return;
    int c = t / Fin;
    int i = t % Fin;
    int kk = c / Fout, o = c % Fout;
    int split = o / CH;
    int cp = split * (Kc * CH) + kk * CH + (o % CH);
    int ct = cp >> 4, lr = cp & 15;
    int step = i >> 5, rem = i & 31, lg = rem >> 3, jj = rem & 7;
    size_t dst = ((((size_t)ct * ksteps + step) * 4 + lg) * 16 + lr) * 8 + jj;
    BF[dst] = f2b(W[((size_t)kk * Fin + i) * Fout + o]);
}

// conv1 phase B: W1 in LDS; wave per row-node; streams row-sorted basisR/idxR.
__global__ __launch_bounds__(512) void phaseB1s_kernel(
        const float* __restrict__ W1, const float* __restrict__ basisR,
        const unsigned char* __restrict__ idxR, const int* __restrict__ rowStart,
        const int* __restrict__ histR, const float* __restrict__ b1,
        unsigned short* __restrict__ h1b, int N) {
    __shared__ float w[125 * 64];
    for (int i = threadIdx.x; i < 125 * 64; i += 512) w[i] = W1[i];
    __syncthreads();
    int n = blockIdx.x * 8 + (threadIdx.x >> 6);
    if (n >= N) return;
    int l = threadIdx.x & 63;
    int s0 = rowStart[n], cnt = histR[n];
    float a = 0.0f;
    for (int i = 0; i < cnt; ++i) {
        const float4* bp = (const float4*)(basisR + (size_t)(s0 + i) * 8);
        float4 b0 = bp[0], b1v = bp[1];
        const uchar4* ip = (const uchar4*)(idxR + (size_t)(s0 + i) * 8);
        uchar4 i0 = ip[0], i1 = ip[1];
        a += b0.x * w[i0.x * 64 + l] + b0.y * w[i0.y * 64 + l]
           + b0.z * w[i0.z * 64 + l] + b0.w * w[i0.w * 64 + l]
           + b1v.x * w[i1.x * 64 + l] + b1v.y * w[i1.y * 64 + l]
           + b1v.z * w[i1.z * 64 + l] + b1v.w * w[i1.w * 64 + l];
    }
    float v = a / fmaxf((float)cnt, 1.0f) + b1[l];
    v = (v > 0.0f) ? v : (expf(v) - 1.0f);
    h1b[(size_t)n * 64 + l] = f2b(v);
}

// fused conv: 1024 threads (16 waves), block owns 16 col-nodes (exact MFMA
// row-tile). Per split s (CH=16): MFMA fills ztile[16][2000] fp16; edge pass
// (128 grp x 8 ch-pairs) packed-fp16 math -> msgP[s] at rs[j].
template<int KSTEPS, int SPLITS>
__global__ __launch_bounds__(1024) void fusedconv_kernel(
        const unsigned short* __restrict__ A,
        const unsigned short* __restrict__ BF,
        const unsigned int* __restrict__ basisH, const unsigned char* __restrict__ idxb,
        const int* __restrict__ cstart, const int* __restrict__ colS,
        const int* __restrict__ rs,
        unsigned short* __restrict__ msgP, int N, int E) {
    const int ZLD = 2008;
    __shared__ unsigned short ztile[16 * 2008];   // 64,256 B
    int n0 = blockIdx.x * 16;
    if (n0 >= N) return;
    int w = threadIdx.x >> 6, l = threadIdx.x & 63;
    int lr = l & 15, lg = l >> 4;
    const int KD = KSTEPS * 32;
    int arow = n0 + lr; if (arow > N - 1) arow = N - 1;
    s16x8 a[KSTEPS];
#pragma unroll
    for (int st = 0; st < KSTEPS; ++st)
        a[st] = *(const s16x8*)(A + (size_t)arow * KD + st * 32 + lg * 8);
    int estart = cstart[n0];
    int eend = (n0 + 16 < N) ? cstart[n0 + 16] : E;
    int g = threadIdx.x >> 3, chp = threadIdx.x & 7;   // 128 groups x 8 ch-pairs
    for (int s = 0; s < SPLITS; ++s) {
        for (int ct = w; ct < 125; ct += 16) {
            f32x4 acc = (f32x4){0.f, 0.f, 0.f, 0.f};
#pragma unroll
            for (int st = 0; st < KSTEPS; ++st) {
                const unsigned short* bp =
                    BF + ((((size_t)(s * 125 + ct) * KSTEPS + st) * 4 + lg) * 16 + lr) * 8;
                s16x8 b = *(const s16x8*)bp;
                acc = __builtin_amdgcn_mfma_f32_16x16x32_bf16(a[st], b, acc, 0, 0, 0);
            }
#pragma unroll
            for (int r = 0; r < 4; ++r)
                ztile[(lg * 4 + r) * ZLD + ct * 16 + lr] = f2h(acc[r]);
        }
        __syncthreads();
        unsigned int* mp = (unsigned int*)(msgP + (size_t)s * E * 16);
        for (int j = estart + g; j < eend; j += 128) {
            int node = colS[j] - n0;
            const uint4* bhp = (const uint4*)(basisH + (size_t)j * 8);
            uint4 bA = bhp[0], bB = bhp[1];
            const uchar4* ip = (const uchar4*)(idxb + (size_t)j * 8);
            uchar4 i0 = ip[0], i1 = ip[1];
            const unsigned int* zr = (const unsigned int*)(ztile + node * ZLD);
            unsigned int v0 = zr[i0.x * 8 + chp];
            unsigned int v1 = zr[i0.y * 8 + chp];
            unsigned int v2 = zr[i0.z * 8 + chp];
            unsigned int v3 = zr[i0.w * 8 + chp];
            unsigned int v4 = zr[i1.x * 8 + chp];
            unsigned int v5 = zr[i1.y * 8 + chp];
            unsigned int v6 = zr[i1.z * 8 + chp];
            unsigned int v7 = zr[i1.w * 8 + chp];
            h16x2 ta = u2h2(bA.x) * u2h2(v0);
            ta = u2h2(bA.y) * u2h2(v1) + ta;
            ta = u2h2(bA.z) * u2h2(v2) + ta;
            ta = u2h2(bA.w) * u2h2(v3) + ta;
            h16x2 tb = u2h2(bB.x) * u2h2(v4);
            tb = u2h2(bB.y) * u2h2(v5) + tb;
            tb = u2h2(bB.z) * u2h2(v6) + tb;
            tb = u2h2(bB.w) * u2h2(v7) + tb;
            h16x2 m = ta + tb;
            mp[(size_t)rs[j] * 8 + chp] = __builtin_bit_cast(unsigned int, m);
        }
        __syncthreads();
    }
}

// phase B conv2 + fused stn3/stn4 -> tt. Reads 4 split-major msg planes.
__global__ __launch_bounds__(256) void phaseBs2stn_kernel(
        const unsigned short* __restrict__ msgP, const int* __restrict__ rowStart,
        const int* __restrict__ histR, const float* __restrict__ b2,
        const float* __restrict__ w3, const float* __restrict__ b3,
        const float* __restrict__ w4, const float* __restrict__ b4,
        float* __restrict__ tt, int N, int E) {
    __shared__ float sh[4][64];
    __shared__ float sh3[4][64];
    int wid = threadIdx.x >> 6, l = threadIdx.x & 63;
    int n = blockIdx.x * 4 + wid;
    if (n >= N) return;
    int s0 = rowStart[n], cnt = histR[n];
    const unsigned short* mp = msgP + (size_t)(l >> 4) * E * 16 + (l & 15);
    float a = 0.0f;
    for (int i = 0; i < cnt; ++i)
        a += h2f(mp[(size_t)(s0 + i) * 16]);
    float v = a / fmaxf((float)cnt, 1.0f) + b2[l];
    v = (v > 0.0f) ? v : (expf(v) - 1.0f);
    sh[wid][l] = v;
    __builtin_amdgcn_wave_barrier();
    float v3 = b3[l];
#pragma unroll
    for (int i = 0; i < 64; ++i) v3 += sh[wid][i] * w3[i * 64 + l];
    v3 = (v3 > 0.0f) ? v3 : (expf(v3) - 1.0f);
    sh3[wid][l] = v3;
    __builtin_amdgcn_wave_barrier();
    if (l < 3) {
        float tv = b4[l];
#pragma unroll
        for (int i = 0; i < 64; ++i) tv += sh3[wid][i] * w4[i * 3 + l];
        tt[(size_t)n * 3 + l] = tv;
    }
}

// phase B conv3: half-wave per node; reads 2 split-major planes; mean+bias.
__global__ __launch_bounds__(256) void phaseBs3p_kernel(
        const unsigned short* __restrict__ msgP, const int* __restrict__ rowStart,
        const int* __restrict__ histR, const float* __restrict__ bias,
        float* __restrict__ out, int N, int E) {
    int n = blockIdx.x * 8 + (threadIdx.x >> 5);
    if (n >= N) return;
    int l = threadIdx.x & 31;
    int s0 = rowStart[n], cnt = histR[n];
    const unsigned short* mp = msgP + (size_t)(l >> 4) * E * 16 + (l & 15);
    float a = 0.0f;
    for (int i = 0; i < cnt; ++i)
        a += h2f(mp[(size_t)(s0 + i) * 16]);
    out[(size_t)n * 32 + l] = a / fmaxf((float)cnt, 1.0f) + bias[l];
}

// stn3 + stn4 per node (fallback path only)
__global__ __launch_bounds__(64) void stn34_kernel(
        const float* __restrict__ h2, const float* __restrict__ w3,
        const float* __restrict__ b3, const float* __restrict__ w4,
        const float* __restrict__ b4, float* __restrict__ t, int N) {
    int n = blockIdx.x;
    int o = threadIdx.x;
    __shared__ float sh[64];
    __shared__ float sh3[64];
    sh[o] = h2[n * 64 + o];
    __syncthreads();
    float v = b3[o];
#pragma unroll
    for (int i = 0; i < 64; ++i) v += sh[i] * w3[i * 64 + o];
    v = (v > 0.0f) ? v : (expf(v) - 1.0f);
    sh3[o] = v;
    __syncthreads();
    if (o < 3) {
        float tv = b4[o];
#pragma unroll
        for (int i = 0; i < 64; ++i) tv += sh3[i] * w4[i * 3 + o];
        t[n * 3 + o] = tv;
    }
}

// ---- minimal fallback (only if ws is tiny; direct, correct) ----
__global__ __launch_bounds__(256) void conv1_at_kernel(
        const float* __restrict__ basis, const unsigned char* __restrict__ idxb,
        const int* __restrict__ row, const float* __restrict__ W1,
        float* __restrict__ acc, int E) {
    int j = blockIdx.x * 4 + (threadIdx.x >> 6);
    if (j >= E) return;
    int l = threadIdx.x & 63;
    float m = 0.0f;
#pragma unroll
    for (int s = 0; s < 8; ++s) m += basis[(size_t)j * 8 + s] * W1[idxb[(size_t)j * 8 + s] * 64 + l];
    atomicAdd(&acc[(size_t)row[j] * 64 + l], m);
}

__global__ __launch_bounds__(256) void conv2f_kernel(
        const float* __restrict__ h1, const float* __restrict__ basis,
        const unsigned char* __restrict__ idxb, const int* __restrict__ row,
        const int* __restrict__ col, const float* __restrict__ W2,
        float* __restrict__ acc, int E) {
    int wid = threadIdx.x >> 6;
    int lane = threadIdx.x & 63;
    int e = blockIdx.x * 4 + wid;
    __shared__ float sh[4][64];
    bool active = (e < E);
    int c = active ? col[e] : 0;
    if (active) sh[wid][lane] = h1[(size_t)c * 64 + lane];
    __syncthreads();
    if (!active) return;
    float m = 0.0f;
#pragma unroll
    for (int s = 0; s < 8; ++s) {
        const float* Wk = W2 + (size_t)idxb[(size_t)e * 8 + s] * 4096;
        float ms = 0.0f;
#pragma unroll
        for (int i = 0; i < 64; ++i) ms += sh[wid][i] * Wk[i * 64 + lane];
        m += basis[(size_t)e * 8 + s] * ms;
    }
    atomicAdd(&acc[(size_t)row[e] * 64 + lane], m);
}

__global__ __launch_bounds__(256) void conv3f_kernel(
        const float* __restrict__ x, const float* __restrict__ basis,
        const unsigned char* __restrict__ idxb, const int* __restrict__ row,
        const int* __restrict__ col, const float* __restrict__ Wc,
        float* __restrict__ acc, int E) {
    int wid = threadIdx.x >> 6;
    int lane = threadIdx.x & 63;
    int e = blockIdx.x * 4 + wid;
    __shared__ float sx[4][32];
    bool active = (e < E);
    int c = active ? col[e] : 0;
    if (active && lane < 32) sx[wid][lane] = x[(size_t)c * 32 + lane];
    __syncthreads();
    int half = lane >> 5;
    int o = lane & 31;
    float m = 0.0f;
    if (active) {
#pragma unroll
        for (int s2 = 0; s2 < 4; ++s2) {
            int s = half * 4 + s2;
            const float* Wk = Wc + (size_t)idxb[(size_t)e * 8 + s] * 1024;
            float ms = 0.0f;
#pragma unroll
            for (int i = 0; i < 32; ++i) ms += sx[wid][i] * Wk[i * 32 + o];
            m += basis[(size_t)e * 8 + s] * ms;
        }
    }
    m += __shfl_xor(m, 32);
    if (active && lane < 32) atomicAdd(&acc[(size_t)row[e] * 32 + o], m);
}

__global__ void finalize_kernel(const float* __restrict__ acc, const int* __restrict__ histR,
                                const float* __restrict__ bias, float* __restrict__ outF,
                                unsigned short* __restrict__ outB,
                                int N, int F, int do_elu) {
    int t = blockIdx.x * blockDim.x + threadIdx.x;
    if (t >= N * F) return;
    int n = t / F, o = t % F;
    float v = acc[t] / fmaxf((float)histR[n], 1.0f) + bias[o];
    if (do_elu) v = (v > 0.0f) ? v : (expf(v) - 1.0f);
    if (outF) outF[t] = v;
    if (outB) outB[t] = f2b(v);
}

extern "C" void kernel_launch(void* const* d_in, const int* in_sizes, int n_in,
                              void* d_out, int out_size, void* d_ws, size_t ws_size,
                              hipStream_t stream) {
    const float* x      = (const float*)d_in[0];
    const int*   ei     = (const int*)d_in[1];
    const float* pseudo = (const float*)d_in[2];
    const float* w1     = (const float*)d_in[3];
    const float* b1     = (const float*)d_in[4];
    const float* w2     = (const float*)d_in[5];
    const float* b2     = (const float*)d_in[6];
    const float* w3     = (const float*)d_in[7];
    const float* b3     = (const float*)d_in[8];
    const float* w4     = (const float*)d_in[9];
    const float* b4     = (const float*)d_in[10];
    const float* wc     = (const float*)d_in[11];
    const float* cb     = (const float*)d_in[12];
    float* out = (float*)d_out;

    const int N = in_sizes[0] / 32;
    const int E = in_sizes[1] / 2;
    const int* row = ei;
    const int* col = ei + E;
    const int KC = 125;

    char* p = (char*)d_ws;
    // zeroed: histograms
    int* histR = (int*)p; p += (size_t)N * sizeof(int);
    int* histC = (int*)p; p += (size_t)N * sizeof(int);
    size_t zero_bytes = (size_t)(p - (char*)d_ws);
    // non-zeroed
    int* cstart   = (int*)p; p += (size_t)N * sizeof(int);
    int* cursorC  = (int*)p; p += (size_t)N * sizeof(int);
    int* rowStart = (int*)p; p += (size_t)N * sizeof(int);
    int* cursorR  = (int*)p; p += (size_t)N * sizeof(int);
    int* jpos = (int*)p; p += (size_t)E * sizeof(int);
    int* colS = (int*)p; p += (size_t)E * sizeof(int);
    int* rs   = (int*)p; p += (size_t)E * sizeof(int);
    float* tt = (float*)p; p += (size_t)N * 3 * sizeof(float);
    // col-sorted basis: fp16-dup u32 in fast path; f32 in fallback (same bytes)
    unsigned int* basisH = (unsigned int*)p;
    float* basisF = (float*)p; p += (size_t)E * 8 * sizeof(float);
    unsigned char* idxb = (unsigned char*)p; p += (size_t)E * 8;
    unsigned short* h1b = (unsigned short*)p; p += (size_t)N * 64 * sizeof(short);
    unsigned short* xb  = (unsigned short*)p; p += (size_t)N * 32 * sizeof(short);
    unsigned short* BF2 = (unsigned short*)p; p += (size_t)KC * 64 * 64 * sizeof(short);
    unsigned short* BF3 = (unsigned short*)p; p += (size_t)KC * 32 * 32 * sizeof(short);
    unsigned short* msg = (unsigned short*)p; p += (size_t)E * 64 * sizeof(short);
    float* basisR = (float*)p; p += (size_t)E * 8 * sizeof(float);
    unsigned char* idxR = (unsigned char*)p; p += (size_t)E * 8;
    size_t fixed = (size_t)(p - (char*)d_ws);
    bool fast = ws_size >= fixed;

    hipMemsetAsync(d_ws, 0, zero_bytes, stream);
    hist_kernel<<<(E + 255) / 256, 256, 0, stream>>>(row, col, histR, histC, E);

    if (fast) {
        pack_w_kernel<<<(KC * 64 * 64 + 255) / 256, 256, 0, stream>>>(w2, BF2, KC, 64, 64, 2, 16);
        pack_w_kernel<<<(KC * 32 * 32 + 255) / 256, 256, 0, stream>>>(wc, BF3, KC, 32, 32, 1, 16);
        castbf_kernel<<<(N * 32 + 255) / 256, 256, 0, stream>>>(x, xb, N * 32);

        scan2_kernel<<<1, 1024, 0, stream>>>(histC, histR, cstart, cursorC, rowStart, cursorR, N);
        scatterbasis_kernel<<<(E + 255) / 256, 256, 0, stream>>>(
            row, col, pseudo, cursorC, cursorR, jpos, colS, rs, basisH, idxb, basisR, idxR, E);

        // conv1: streaming row-sorted basis vs LDS W1 (512 thr, 32 waves/CU)
        phaseB1s_kernel<<<(N + 7) / 8, 512, 0, stream>>>(w1, basisR, idxR, rowStart,
                                                         histR, b1, h1b, N);
        const int NB = (N + 15) / 16;
        // conv2: fused MFMA-in-LDS, 4 splits, 1024 threads, NODES=16
        fusedconv_kernel<2, 4><<<NB, 1024, 0, stream>>>(
            h1b, BF2, basisH, idxb, cstart, colS, rs, msg, N, E);
        phaseBs2stn_kernel<<<(N + 3) / 4, 256, 0, stream>>>(msg, rowStart, histR, b2,
                                                            w3, b3, w4, b4, tt, N, E);
        basis2h_kernel<<<(E + 255) / 256, 256, 0, stream>>>(pseudo, tt, row, col, jpos,
                                                            basisH, idxb, E);
        // conv3: fused MFMA-in-LDS, 2 splits, 1024 threads, NODES=16
        fusedconv_kernel<1, 2><<<NB, 1024, 0, stream>>>(
            xb, BF3, basisH, idxb, cstart, colS, rs, msg, N, E);
        phaseBs3p_kernel<<<(N + 7) / 8, 256, 0, stream>>>(msg, rowStart, histR, cb, out, N, E);
    } else {
        // tiny-ws fallback: direct convs with atomics (correct, slow)
        float* acc1 = (float*)msg;
        float* acc2 = acc1 + (size_t)N * 64;
        float* acc3 = acc2 + (size_t)N * 64;
        float* h1f  = acc3 + (size_t)N * 32;
        float* h2f_ = h1f  + (size_t)N * 64;
        size_t acc_bytes = (size_t)N * (64 + 64 + 32) * sizeof(float);
        hipMemsetAsync((void*)acc1, 0, acc_bytes, stream);

        basis1_kernel<<<(E + 255) / 256, 256, 0, stream>>>(pseudo, nullptr, basisF, idxb, E);
        conv1_at_kernel<<<(E + 3) / 4, 256, 0, stream>>>(basisF, idxb, row, w1, acc1, E);
        finalize_kernel<<<(N * 64 + 255) / 256, 256, 0, stream>>>(acc1, histR, b1, h1f, nullptr, N, 64, 1);
        conv2f_kernel<<<(E + 3) / 4, 256, 0, stream>>>(h1f, basisF, idxb, row, col, w2, acc2, E);
        finalize_kernel<<<(N * 64 + 255) / 256, 256, 0, stream>>>(acc2, histR, b2, h2f_, nullptr, N, 64, 1);
        stn34_kernel<<<N, 64, 0, stream>>>(h2f_, w3, b3, w4, b4, tt, N);
        basis2_kernel<<<(E + 255) / 256, 256, 0, stream>>>(pseudo, tt, row, col, basisF, idxb, E);
        conv3f_kernel<<<(E + 3) / 4, 256, 0, stream>>>(x, basisF, idxb, row, col, wc, acc3, E);
        finalize_kernel<<<(N * 32 + 255) / 256, 256, 0, stream>>>(acc3, histR, cb, out, nullptr, N, 32, 0);
    }
}